// Round 8
// baseline (4424.215 us; speedup 1.0000x reference)
//
#include <hip/hip_runtime.h>
#include <math.h>

// Problem constants: B=4, T=1024, D=512, G=4*D=2048, V=32000
// Workspace layout:
//   [0,8M)     x / hs2   [4096,512] f32  (hs2 only used on fallback path)
//   [8M,40M)   xg1       [4096,2048] f32
//   [40M,48M)  h1c       [T][512][4] f32  sentinel comm buffer L1
//   [48M,56M)  h2c       [T][512][4] f32  sentinel comm buffer L2
//   [56M,+4K)  progress  [64] u32 (L2 WG step counters, memset 0)
//   [57M,65M)  A'        [4096][1024] bf16 pairs (ah,ah)   } only if
//   [66M,129M) W'        [32000][1024] bf16 pairs (wh,wl)  } ws_size >= 132MiB

#define TSEQ 1024
#define DIM  512
#define GDIM 2048
#define VOC  32000
#define KP   1024
#define SENT 0x7F7F7F7Fu

typedef unsigned uint4v __attribute__((ext_vector_type(4)));
typedef float    f4v    __attribute__((ext_vector_type(4)));
typedef short    short8 __attribute__((ext_vector_type(8)));
typedef float    f32x4  __attribute__((ext_vector_type(4)));

// Agent-scope (sc1 bypasses the non-coherent per-XCD L2s) 16B sentinel poll.
__device__ __forceinline__ uint4v poll_load16(const unsigned* p) {
    uint4v v;
    asm volatile("global_load_dwordx4 %0, %1, off sc1\n\t"
                 "s_waitcnt vmcnt(0)"
                 : "=v"(v) : "v"(p) : "memory");
    return v;
}
// sc1 16B load (A' reads must bypass the reader-XCD L2, like the h-protocol)
__device__ __forceinline__ short8 ld16_sc1(const unsigned short* p) {
    short8 v;
    asm volatile("global_load_dwordx4 %0, %1, off sc1\n\t"
                 "s_waitcnt vmcnt(0)"
                 : "=v"(v) : "v"(p) : "memory");
    return v;
}
__device__ __forceinline__ unsigned ld4_sc1(const unsigned* p) {
    unsigned v;
    asm volatile("global_load_dword %0, %1, off sc1\n\t"
                 "s_waitcnt vmcnt(0)"
                 : "=v"(v) : "v"(p) : "memory");
    return v;
}

// fast sigmoid/tanh via v_exp_f32 + v_rcp_f32 (~1e-6 abs err)
__device__ __forceinline__ float fsig(float x) {
    return __builtin_amdgcn_rcpf(1.0f + __expf(-x));
}
__device__ __forceinline__ float ftanh_(float x) {
    return 1.0f - 2.0f * __builtin_amdgcn_rcpf(1.0f + __expf(2.0f * x));
}

// f32 -> bf16 RNE, and back
__device__ __forceinline__ unsigned short f2bf(float x) {
    unsigned u = __builtin_bit_cast(unsigned, x);
    return (unsigned short)((u + 0x7FFFu + ((u >> 16) & 1u)) >> 16);
}
__device__ __forceinline__ float bf2f(unsigned short h) {
    return __builtin_bit_cast(float, (unsigned)h << 16);
}

// ---------------------------------------------------------------------------
__global__ void embed_kernel(const int* __restrict__ tokens,
                             const float* __restrict__ embed,
                             float* __restrict__ x)
{
    const int row = blockIdx.x;
    const int b = row >> 10;
    const int t = row & 1023;
    const int tok = (t == 0) ? 0 : tokens[b * TSEQ + t - 1];
    const float4* src = (const float4*)(embed + (size_t)tok * DIM);
    float4* dst = (float4*)(x + (size_t)row * DIM);
    dst[threadIdx.x] = src[threadIdx.x];
}

// ---------------------------------------------------------------------------
// fp32 GEMM with bias (xg1 + fallback logits)
// ---------------------------------------------------------------------------
__global__ __launch_bounds__(256) void gemm_bias_f32(
    const float* __restrict__ A, const float* __restrict__ Bm,
    const float* __restrict__ bias, float* __restrict__ C,
    int M, int N, int K)
{
    constexpr int BK = 16;
    __shared__ float As[BK][128 + 4];
    __shared__ float Bs[BK][128 + 4];

    const int tid = threadIdx.x;
    const int m0 = blockIdx.y * 128;
    const int n0 = blockIdx.x * 128;
    const int tm = (tid >> 4) << 3;
    const int tn = (tid & 15) << 3;

    const int a_r = tid >> 2;
    const int a_c = (tid & 3) << 2;
    const int b_r = tid >> 5;
    const int b_c = (tid & 31) << 2;

    float acc[8][8] = {};

    for (int k0 = 0; k0 < K; k0 += BK) {
        const float4 av0 = *(const float4*)&A[(size_t)(m0 + a_r) * K + k0 + a_c];
        const float4 av1 = *(const float4*)&A[(size_t)(m0 + a_r + 64) * K + k0 + a_c];
        const float4 bv0 = *(const float4*)&Bm[(size_t)(k0 + b_r) * N + n0 + b_c];
        const float4 bv1 = *(const float4*)&Bm[(size_t)(k0 + b_r + 8) * N + n0 + b_c];
        __syncthreads();
        As[a_c + 0][a_r] = av0.x;  As[a_c + 1][a_r] = av0.y;
        As[a_c + 2][a_r] = av0.z;  As[a_c + 3][a_r] = av0.w;
        As[a_c + 0][a_r + 64] = av1.x;  As[a_c + 1][a_r + 64] = av1.y;
        As[a_c + 2][a_r + 64] = av1.z;  As[a_c + 3][a_r + 64] = av1.w;
        *(float4*)&Bs[b_r][b_c] = bv0;
        *(float4*)&Bs[b_r + 8][b_c] = bv1;
        __syncthreads();

        #pragma unroll
        for (int kk = 0; kk < BK; ++kk) {
            float a[8], bf[8];
            *(float4*)&a[0]  = *(const float4*)&As[kk][tm];
            *(float4*)&a[4]  = *(const float4*)&As[kk][tm + 4];
            *(float4*)&bf[0] = *(const float4*)&Bs[kk][tn];
            *(float4*)&bf[4] = *(const float4*)&Bs[kk][tn + 4];
            #pragma unroll
            for (int i = 0; i < 8; ++i)
                #pragma unroll
                for (int jx = 0; jx < 8; ++jx)
                    acc[i][jx] += a[i] * bf[jx];
        }
    }

    float bv[8];
    #pragma unroll
    for (int jx = 0; jx < 8; ++jx) bv[jx] = bias[n0 + tn + jx];

    #pragma unroll
    for (int i = 0; i < 8; ++i) {
        float* crow = C + (size_t)(m0 + tm + i) * N + (n0 + tn);
        float4 o0, o1;
        o0.x = acc[i][0] + bv[0]; o0.y = acc[i][1] + bv[1];
        o0.z = acc[i][2] + bv[2]; o0.w = acc[i][3] + bv[3];
        o1.x = acc[i][4] + bv[4]; o1.y = acc[i][5] + bv[5];
        o1.z = acc[i][6] + bv[6]; o1.w = acc[i][7] + bv[7];
        *(float4*)&crow[0] = o0;
        *(float4*)&crow[4] = o1;
    }
}

// ---------------------------------------------------------------------------
// W[512][32000] f32 -> W'[32000][1024] bf16 pairs (wh, wl)   [R5, verified]
// ---------------------------------------------------------------------------
__global__ __launch_bounds__(256) void transpose_W(const float* __restrict__ W,
                                                   unsigned short* __restrict__ Wt)
{
    __shared__ float tile[32][256];
    const int tid = threadIdx.x;
    const int n0 = blockIdx.x * 256;
    const int k0 = blockIdx.y * 32;

    #pragma unroll 8
    for (int r = 0; r < 32; ++r)
        tile[r][tid] = W[(size_t)(k0 + r) * VOC + n0 + tid];
    __syncthreads();

    unsigned short pr[64];
    #pragma unroll
    for (int kk = 0; kk < 32; ++kk) {
        const float w = tile[kk][tid];
        const unsigned short h = f2bf(w);
        const unsigned short l = f2bf(w - bf2f(h));
        pr[2 * kk + 0] = h;
        pr[2 * kk + 1] = l;
    }
    unsigned short* dst = Wt + (size_t)(n0 + tid) * KP + 2 * k0;
    #pragma unroll
    for (int i = 0; i < 8; ++i)
        *(short8*)(dst + 8 * i) = *(short8*)&pr[8 * i];
}

// ---------------------------------------------------------------------------
// MEGA kernel: 128 LSTM blocks (R7's verbatim 2.95ms loops) + 8000 logits
// blocks consuming L2 output progressively on the otherwise-idle CUs.
//   - LDS padded to 84KB -> exactly 1 WG/CU: logits can never co-schedule
//     onto an lstm CU and perturb the latency-critical poll loops.
//   - L2 finishers write A' bf16-pairs (agent scope) and publish
//     progress[wg]=t+1 after a wave-local vmcnt(0) drain (release).
//   - Logits block (tw,b,n) spins on the 64 progress counters until
//     all >= tw*128+128, then runs the R5-verified split-bf16 GEMM
//     (512-thread variant). A' reads via sc1 (bypass reader L2).
//   - Block order: lstm 0..127 first (all resident -> no deadlock), logits
//     ordered tw-ascending = readiness order.
// ---------------------------------------------------------------------------
__global__ __launch_bounds__(512, 1) void mega_kernel(
    const float* __restrict__ xg1, const float* __restrict__ Wh0,
    const float* __restrict__ Wx1, const float* __restrict__ Wh1,
    const float* __restrict__ b1,
    float* __restrict__ h1c, float* __restrict__ h2c,
    float* __restrict__ hs2,
    unsigned* __restrict__ progress,
    unsigned short* __restrict__ Ab, const unsigned short* __restrict__ Wb,
    const float* __restrict__ bout, float* __restrict__ out,
    int use_mfma)
{
    __shared__ __align__(16) char smem[86016];   // 84KB: forces 1 WG/CU

    const int tid = threadIdx.x;

    if (blockIdx.x < 128) {
        // =================== LSTM (R7 verbatim structure) ===================
        f4v*   hA       = (f4v*)smem;                       // 8KB
        f4v*   hB       = (f4v*)(smem + 8192);              // 8KB
        float* partf    = (float*)(smem + 16384);           // part[16][4][32]
        float* gate_lds = (float*)(smem + 24576);           // [4][32]

        const int layer = blockIdx.x >> 6;
        const int wg    = blockIdx.x & 63;
        const int dbase = wg * 8;
        const int j = tid & 31;
        const int s = tid >> 5;
        const int wcol = (j >> 3) * DIM + dbase + (j & 7);

        float wr[32], wx[32];
        {
            const float* Wrec = layer ? Wh1 : Wh0;
            #pragma unroll
            for (int r = 0; r < 32; ++r)
                wr[r] = Wrec[(size_t)(s * 32 + r) * GDIM + wcol];
            if (layer) {
                #pragma unroll
                for (int r = 0; r < 32; ++r)
                    wx[r] = Wx1[(size_t)(s * 32 + r) * GDIM + wcol];
            }
        }
        float bias2 = 0.f;
        if (layer && tid < 128) bias2 = b1[wcol];

        float c_reg = 0.f;
        const unsigned* h1u = (const unsigned*)h1c;
        const unsigned* h2u = (const unsigned*)h2c;
        unsigned* Au = (unsigned*)Ab;

        if (layer == 0) {
            for (int t = 0; t < TSEQ; ++t) {
                float xgv = 0.f;
                if (tid < 128) xgv = xg1[((size_t)s * TSEQ + t) * GDIM + wcol];

                if (t > 0) {
                    const unsigned* p = h1u + ((size_t)(t - 1) * DIM + tid) * 4;
                    uint4v u;
                    do { u = poll_load16(p); }
                    while (u.x == SENT || u.y == SENT || u.z == SENT || u.w == SENT);
                    hA[tid] = __builtin_bit_cast(f4v, u);
                } else {
                    hA[tid] = f4v{0.f, 0.f, 0.f, 0.f};
                }
                __syncthreads();

                float a0 = 0.f, a1 = 0.f, a2 = 0.f, a3 = 0.f;
                const f4v* hp = &hA[s * 32];
                #pragma unroll
                for (int r = 0; r < 32; ++r) {
                    const f4v v = hp[r];
                    a0 += v.x * wr[r]; a1 += v.y * wr[r];
                    a2 += v.z * wr[r]; a3 += v.w * wr[r];
                }
                partf[(s * 4 + 0) * 32 + j] = a0; partf[(s * 4 + 1) * 32 + j] = a1;
                partf[(s * 4 + 2) * 32 + j] = a2; partf[(s * 4 + 3) * 32 + j] = a3;
                __syncthreads();

                if (tid < 128) {
                    float sum = xgv;
                    #pragma unroll
                    for (int s2 = 0; s2 < 16; ++s2) sum += partf[(s2 * 4 + s) * 32 + j];
                    gate_lds[s * 32 + j] = sum;
                }
                __syncthreads();

                if (tid < 32) {
                    const int ub = tid >> 3, ud = tid & 7;
                    const float iv = gate_lds[ub * 32 +  0 + ud];
                    const float fv = gate_lds[ub * 32 +  8 + ud];
                    const float gv = gate_lds[ub * 32 + 16 + ud];
                    const float ov = gate_lds[ub * 32 + 24 + ud];
                    const float ig = fsig(iv);
                    const float fg = fsig(fv);
                    const float og = fsig(ov);
                    c_reg = fg * c_reg + ig * ftanh_(gv);
                    const float hval = og * ftanh_(c_reg);
                    __hip_atomic_store(&h1c[((size_t)t * DIM + dbase + ud) * 4 + ub],
                                       hval, __ATOMIC_RELAXED, __HIP_MEMORY_SCOPE_AGENT);
                }
            }
        } else {
            for (int t = 0; t < TSEQ; ++t) {
                if (t > 0) {
                    const unsigned* p = h2u + ((size_t)(t - 1) * DIM + tid) * 4;
                    uint4v u;
                    do { u = poll_load16(p); }
                    while (u.x == SENT || u.y == SENT || u.z == SENT || u.w == SENT);
                    hB[tid] = __builtin_bit_cast(f4v, u);
                } else {
                    hB[tid] = f4v{0.f, 0.f, 0.f, 0.f};
                }
                __syncthreads();

                float a0 = 0.f, a1 = 0.f, a2 = 0.f, a3 = 0.f;
                {
                    const f4v* hp = &hB[s * 32];
                    #pragma unroll
                    for (int r = 0; r < 32; ++r) {
                        const f4v v = hp[r];
                        a0 += v.x * wr[r]; a1 += v.y * wr[r];
                        a2 += v.z * wr[r]; a3 += v.w * wr[r];
                    }
                }
                {
                    const unsigned* p = h1u + ((size_t)t * DIM + tid) * 4;
                    uint4v u;
                    do { u = poll_load16(p); }
                    while (u.x == SENT || u.y == SENT || u.z == SENT || u.w == SENT);
                    hA[tid] = __builtin_bit_cast(f4v, u);
                }
                __syncthreads();
                {
                    const f4v* hp = &hA[s * 32];
                    #pragma unroll
                    for (int r = 0; r < 32; ++r) {
                        const f4v v = hp[r];
                        a0 += v.x * wx[r]; a1 += v.y * wx[r];
                        a2 += v.z * wx[r]; a3 += v.w * wx[r];
                    }
                }
                partf[(s * 4 + 0) * 32 + j] = a0; partf[(s * 4 + 1) * 32 + j] = a1;
                partf[(s * 4 + 2) * 32 + j] = a2; partf[(s * 4 + 3) * 32 + j] = a3;
                __syncthreads();

                if (tid < 128) {
                    float sum = bias2;
                    #pragma unroll
                    for (int s2 = 0; s2 < 16; ++s2) sum += partf[(s2 * 4 + s) * 32 + j];
                    gate_lds[s * 32 + j] = sum;
                }
                __syncthreads();

                if (tid < 32) {
                    const int ub = tid >> 3, ud = tid & 7;
                    const float iv = gate_lds[ub * 32 +  0 + ud];
                    const float fv = gate_lds[ub * 32 +  8 + ud];
                    const float gv = gate_lds[ub * 32 + 16 + ud];
                    const float ov = gate_lds[ub * 32 + 24 + ud];
                    const float ig = fsig(iv);
                    const float fg = fsig(fv);
                    const float og = fsig(ov);
                    c_reg = fg * c_reg + ig * ftanh_(gv);
                    const float hval = og * ftanh_(c_reg);
                    __hip_atomic_store(&h2c[((size_t)t * DIM + dbase + ud) * 4 + ub],
                                       hval, __ATOMIC_RELAXED, __HIP_MEMORY_SCOPE_AGENT);
                    if (use_mfma) {
                        const unsigned short ah = f2bf(hval);
                        const unsigned pk = (unsigned)ah | ((unsigned)ah << 16);
                        __hip_atomic_store(&Au[(size_t)(ub * TSEQ + t) * 512 + dbase + ud],
                                           pk, __ATOMIC_RELAXED, __HIP_MEMORY_SCOPE_AGENT);
                    } else {
                        hs2[((size_t)ub * TSEQ + t) * DIM + dbase + ud] = hval;
                    }
                }
                if (use_mfma) {
                    if (tid < 64)
                        asm volatile("s_waitcnt vmcnt(0)" ::: "memory");   // A' drained
                    if (tid == 0)
                        __hip_atomic_store(&progress[wg], (unsigned)(t + 1),
                                           __ATOMIC_RELAXED, __HIP_MEMORY_SCOPE_AGENT);
                }
            }
        }
    } else {
        // =================== LOGITS (split-bf16 MFMA, 512 thr) =============
        unsigned short* As = (unsigned short*)smem;            // 16KB
        unsigned short* Bs = (unsigned short*)(smem + 16384);  // 16KB

        const int job = blockIdx.x - 128;
        const int tw  = job / 1000;           // t-window 0..7 (readiness order)
        const int rem = job % 1000;
        const int bb  = rem / 250;
        const int nn  = rem % 250;
        const int m0  = bb * 1024 + tw * 128;
        const int n0  = nn * 128;

        // wait until L2 has produced t = tw*128+127 everywhere
        const unsigned tneed = (unsigned)(tw * 128 + 128);
        if (tid < 64) {
            const unsigned* pp = progress + tid;
            unsigned v;
            do { v = ld4_sc1(pp); } while (__any(v < tneed));
        }
        __syncthreads();

        const int lane = tid & 63;
        const int w    = tid >> 6;            // 0..7
        const int wm   = w >> 2;              // 0..1 (64-row half)
        const int wn   = w & 3;               // 0..3 (32-col quarter)

        const int srow = tid >> 2;            // 0..127
        const int s0   = (tid & 3) * 2;       // slot base 0,2,4,6
        const unsigned short* gA = Ab + (size_t)(m0 + srow) * KP + s0 * 8;
        const unsigned short* gB = Wb + (size_t)(n0 + srow) * KP + s0 * 8;
        const int swz = srow & 7;

        f32x4 acc[4][2] = {};
        short8 ra[2], rb[2];

        ra[0] = ld16_sc1(gA);
        ra[1] = ld16_sc1(gA + 8);
        rb[0] = *(const short8*)(gB);
        rb[1] = *(const short8*)(gB + 8);

        #pragma unroll 1
        for (int kt = 0; kt < KP / 64; ++kt) {
            __syncthreads();
            #pragma unroll
            for (int c = 0; c < 2; ++c) {
                *(short8*)&As[srow * 64 + ((s0 + c) ^ swz) * 8] = ra[c];
                *(short8*)&Bs[srow * 64 + ((s0 + c) ^ swz) * 8] = rb[c];
            }
            __syncthreads();

            if (kt + 1 < KP / 64) {
                const int ko = (kt + 1) * 64;
                ra[0] = ld16_sc1(gA + ko);
                ra[1] = ld16_sc1(gA + ko + 8);
                rb[0] = *(const short8*)(gB + ko);
                rb[1] = *(const short8*)(gB + ko + 8);
            }

            #pragma unroll
            for (int kk = 0; kk < 2; ++kk) {
                const int q = kk * 4 + (lane >> 4);
                short8 a[4], b[2];
                #pragma unroll
                for (int i = 0; i < 4; ++i) {
                    const int Ra = wm * 64 + i * 16 + (lane & 15);
                    a[i] = *(const short8*)&As[Ra * 64 + (q ^ (Ra & 7)) * 8];
                }
                #pragma unroll
                for (int jx = 0; jx < 2; ++jx) {
                    const int Rb = wn * 32 + jx * 16 + (lane & 15);
                    b[jx] = *(const short8*)&Bs[Rb * 64 + (q ^ (Rb & 7)) * 8];
                }
                #pragma unroll
                for (int i = 0; i < 4; ++i)
                    #pragma unroll
                    for (int jx = 0; jx < 2; ++jx)
                        acc[i][jx] = __builtin_amdgcn_mfma_f32_16x16x32_bf16(
                            a[i], b[jx], acc[i][jx], 0, 0, 0);
            }
        }

        float bv[2];
        #pragma unroll
        for (int jx = 0; jx < 2; ++jx)
            bv[jx] = bout[n0 + wn * 32 + jx * 16 + (lane & 15)];

        #pragma unroll
        for (int i = 0; i < 4; ++i) {
            #pragma unroll
            for (int jx = 0; jx < 2; ++jx) {
                const int col = n0 + wn * 32 + jx * 16 + (lane & 15);
                #pragma unroll
                for (int r = 0; r < 4; ++r) {
                    const int row = m0 + wm * 64 + i * 16 + (lane >> 4) * 4 + r;
                    out[(size_t)row * VOC + col] = acc[i][jx][r] + bv[jx];
                }
            }
        }
    }
}

// ---------------------------------------------------------------------------
extern "C" void kernel_launch(void* const* d_in, const int* in_sizes, int n_in,
                              void* d_out, int out_size, void* d_ws, size_t ws_size,
                              hipStream_t stream)
{
    const int*   tokens = (const int*)d_in[0];
    const float* embed  = (const float*)d_in[1];
    const float* Wx0    = (const float*)d_in[2];
    const float* Wh0    = (const float*)d_in[3];
    const float* b0     = (const float*)d_in[4];
    const float* Wx1    = (const float*)d_in[5];
    const float* Wh1    = (const float*)d_in[6];
    const float* b1     = (const float*)d_in[7];
    const float* Wout   = (const float*)d_in[8];
    const float* bout   = (const float*)d_in[9];
    float* out = (float*)d_out;

    char* ws = (char*)d_ws;
    float*    x        = (float*)(ws);
    float*    xg1      = (float*)(ws + ((size_t)8u << 20));
    float*    h1c      = (float*)(ws + ((size_t)40u << 20));
    float*    h2c      = (float*)(ws + ((size_t)48u << 20));
    unsigned* progress = (unsigned*)(ws + ((size_t)56u << 20));
    unsigned short* At = (unsigned short*)(ws + ((size_t)57u << 20));
    unsigned short* Wt = (unsigned short*)(ws + ((size_t)66u << 20));
    float* hs2 = x;

    const bool use_mfma = ws_size >= ((size_t)132u << 20);

    // sentinel-init comm buffers; zero the progress counters
    hipMemsetAsync(ws + ((size_t)40u << 20), 0x7F, (size_t)16u << 20, stream);
    hipMemsetAsync(progress, 0, 4096, stream);

    embed_kernel<<<dim3(4096), dim3(128), 0, stream>>>(tokens, embed, x);
    gemm_bias_f32<<<dim3(16, 32), dim3(256), 0, stream>>>(x, Wx0, b0, xg1, 4096, 2048, 512);

    if (use_mfma) {
        transpose_W<<<dim3(125, 16), dim3(256), 0, stream>>>(Wout, Wt);
        mega_kernel<<<dim3(128 + 8000), dim3(512), 0, stream>>>(
            xg1, Wh0, Wx1, Wh1, b1, h1c, h2c, hs2, progress, At, Wt, bout, out, 1);
    } else {
        mega_kernel<<<dim3(128), dim3(512), 0, stream>>>(
            xg1, Wh0, Wx1, Wh1, b1, h1c, h2c, hs2, progress, At, Wt, bout, out, 0);
        gemm_bias_f32<<<dim3(250, 32), dim3(256), 0, stream>>>(hs2, Wout, bout, out, 4096, VOC, 512);
    }
}

// Round 9
// 3317.883 us; speedup vs baseline: 1.3334x; 1.3334x over previous
//
#include <hip/hip_runtime.h>
#include <math.h>

// Problem constants: B=4, T=1024, D=512, G=4*D=2048, V=32000
// Workspace layout:
//   [0,8M)     x / hs2   [4096,512] f32
//   [8M,40M)   xg1       [4096,2048] f32
//   [40M,48M)  h1c       [T][512][4] f32  sentinel comm buffer L1
//   [48M,56M)  h2c       [T][512][4] f32  sentinel comm buffer L2
//   [56M,64M)  A'        [4096][1024] bf16 (2-term split)   } only if
//   [64M,130M) W'        [32000][1024] bf16 (2-term split)  } ws_size >= 132MiB

#define TSEQ 1024
#define DIM  512
#define GDIM 2048
#define VOC  32000
#define SENT 0x7F7F7F7Fu

typedef unsigned uint4v __attribute__((ext_vector_type(4)));
typedef float    f4v    __attribute__((ext_vector_type(4)));
typedef short    short8 __attribute__((ext_vector_type(8)));
typedef float    f32x4  __attribute__((ext_vector_type(4)));

// Agent-scope (sc1 bypasses the non-coherent per-XCD L2s) 16B sentinel poll.
__device__ __forceinline__ uint4v poll_load16(const unsigned* p) {
    uint4v v;
    asm volatile("global_load_dwordx4 %0, %1, off sc1\n\t"
                 "s_waitcnt vmcnt(0)"
                 : "=v"(v) : "v"(p) : "memory");
    return v;
}
// T14-style split: fire the load now (no wait) ...
__device__ __forceinline__ void issue_load16(const unsigned* p, uint4v* v) {
    asm volatile("global_load_dwordx4 %0, %1, off sc1"
                 : "=&v"(*v) : "v"(p) : "memory");
}
// ... and complete it later (register kept live across the gap).
__device__ __forceinline__ void wait_load16(uint4v* v) {
    asm volatile("s_waitcnt vmcnt(0)" : "+v"(*v) :: "memory");
}

// fast sigmoid/tanh via v_exp_f32 + v_rcp_f32 (~1e-6 abs err)
__device__ __forceinline__ float fsig(float x) {
    return __builtin_amdgcn_rcpf(1.0f + __expf(-x));
}
__device__ __forceinline__ float ftanh_(float x) {
    return 1.0f - 2.0f * __builtin_amdgcn_rcpf(1.0f + __expf(2.0f * x));
}

// f32 -> bf16 RNE, and back
__device__ __forceinline__ unsigned short f2bf(float x) {
    unsigned u = __builtin_bit_cast(unsigned, x);
    return (unsigned short)((u + 0x7FFFu + ((u >> 16) & 1u)) >> 16);
}
__device__ __forceinline__ float bf2f(unsigned short h) {
    return __builtin_bit_cast(float, (unsigned)h << 16);
}

// ---------------------------------------------------------------------------
__global__ void embed_kernel(const int* __restrict__ tokens,
                             const float* __restrict__ embed,
                             float* __restrict__ x)
{
    const int row = blockIdx.x;
    const int b = row >> 10;
    const int t = row & 1023;
    const int tok = (t == 0) ? 0 : tokens[b * TSEQ + t - 1];
    const float4* src = (const float4*)(embed + (size_t)tok * DIM);
    float4* dst = (float4*)(x + (size_t)row * DIM);
    dst[threadIdx.x] = src[threadIdx.x];
}

// ---------------------------------------------------------------------------
// fp32 GEMM with bias (xg1 + fallback logits)
// ---------------------------------------------------------------------------
__global__ __launch_bounds__(256) void gemm_bias_f32(
    const float* __restrict__ A, const float* __restrict__ Bm,
    const float* __restrict__ bias, float* __restrict__ C,
    int M, int N, int K)
{
    constexpr int BK = 16;
    __shared__ float As[BK][128 + 4];
    __shared__ float Bs[BK][128 + 4];

    const int tid = threadIdx.x;
    const int m0 = blockIdx.y * 128;
    const int n0 = blockIdx.x * 128;
    const int tm = (tid >> 4) << 3;
    const int tn = (tid & 15) << 3;

    const int a_r = tid >> 2;
    const int a_c = (tid & 3) << 2;
    const int b_r = tid >> 5;
    const int b_c = (tid & 31) << 2;

    float acc[8][8] = {};

    for (int k0 = 0; k0 < K; k0 += BK) {
        const float4 av0 = *(const float4*)&A[(size_t)(m0 + a_r) * K + k0 + a_c];
        const float4 av1 = *(const float4*)&A[(size_t)(m0 + a_r + 64) * K + k0 + a_c];
        const float4 bv0 = *(const float4*)&Bm[(size_t)(k0 + b_r) * N + n0 + b_c];
        const float4 bv1 = *(const float4*)&Bm[(size_t)(k0 + b_r + 8) * N + n0 + b_c];
        __syncthreads();
        As[a_c + 0][a_r] = av0.x;  As[a_c + 1][a_r] = av0.y;
        As[a_c + 2][a_r] = av0.z;  As[a_c + 3][a_r] = av0.w;
        As[a_c + 0][a_r + 64] = av1.x;  As[a_c + 1][a_r + 64] = av1.y;
        As[a_c + 2][a_r + 64] = av1.z;  As[a_c + 3][a_r + 64] = av1.w;
        *(float4*)&Bs[b_r][b_c] = bv0;
        *(float4*)&Bs[b_r + 8][b_c] = bv1;
        __syncthreads();

        #pragma unroll
        for (int kk = 0; kk < BK; ++kk) {
            float a[8], bf[8];
            *(float4*)&a[0]  = *(const float4*)&As[kk][tm];
            *(float4*)&a[4]  = *(const float4*)&As[kk][tm + 4];
            *(float4*)&bf[0] = *(const float4*)&Bs[kk][tn];
            *(float4*)&bf[4] = *(const float4*)&Bs[kk][tn + 4];
            #pragma unroll
            for (int i = 0; i < 8; ++i)
                #pragma unroll
                for (int jx = 0; jx < 8; ++jx)
                    acc[i][jx] += a[i] * bf[jx];
        }
    }

    float bv[8];
    #pragma unroll
    for (int jx = 0; jx < 8; ++jx) bv[jx] = bias[n0 + tn + jx];

    #pragma unroll
    for (int i = 0; i < 8; ++i) {
        float* crow = C + (size_t)(m0 + tm + i) * N + (n0 + tn);
        float4 o0, o1;
        o0.x = acc[i][0] + bv[0]; o0.y = acc[i][1] + bv[1];
        o0.z = acc[i][2] + bv[2]; o0.w = acc[i][3] + bv[3];
        o1.x = acc[i][4] + bv[4]; o1.y = acc[i][5] + bv[5];
        o1.z = acc[i][6] + bv[6]; o1.w = acc[i][7] + bv[7];
        *(float4*)&crow[0] = o0;
        *(float4*)&crow[4] = o1;
    }
}

// ---------------------------------------------------------------------------
// Persistent 2-layer pipelined LSTM — R7 structure (2.947ms measured), ONE
// change: L2 fires the h1[t] load at step top (fire-and-forget) and completes
// it after MAC1 (T14 split issue/wait). The WAIT schedule is unchanged: h2
// poll first, h1 consumed after MAC1, fallback poll if sentinel (cold start).
// In steady state L1 leads L2 (P1<P2, L1 never waits), so the early load
// returns real data and the ~500-600cy h1 RT hides under h2-poll + MAC1.
// ---------------------------------------------------------------------------
__global__ __launch_bounds__(512, 1) void lstm2_kernel(
    const float* __restrict__ xg1, const float* __restrict__ Wh0,
    const float* __restrict__ Wx1, const float* __restrict__ Wh1,
    const float* __restrict__ b1,
    float* __restrict__ h1c, float* __restrict__ h2c,
    float* __restrict__ hs2)
{
    const int layer = blockIdx.x >> 6;
    const int wg    = blockIdx.x & 63;
    const int tid   = threadIdx.x;
    const int dbase = wg * 8;
    const int j = tid & 31;
    const int s = tid >> 5;
    const int wcol = (j >> 3) * DIM + dbase + (j & 7);

    __shared__ f4v  hA[DIM];
    __shared__ f4v  hB[DIM];
    __shared__ float part[16][4][32];
    __shared__ float gate_lds[4][32];

    float wr[32], wx[32];
    {
        const float* Wrec = layer ? Wh1 : Wh0;
        #pragma unroll
        for (int r = 0; r < 32; ++r)
            wr[r] = Wrec[(size_t)(s * 32 + r) * GDIM + wcol];
        if (layer) {
            #pragma unroll
            for (int r = 0; r < 32; ++r)
                wx[r] = Wx1[(size_t)(s * 32 + r) * GDIM + wcol];
        }
    }
    float bias2 = 0.f;
    if (layer && tid < 128) bias2 = b1[wcol];

    float c_reg = 0.f;
    const unsigned* h1u = (const unsigned*)h1c;
    const unsigned* h2u = (const unsigned*)h2c;

    if (layer == 0) {
        for (int t = 0; t < TSEQ; ++t) {
            float xgv = 0.f;
            if (tid < 128) xgv = xg1[((size_t)s * TSEQ + t) * GDIM + wcol];

            if (t > 0) {
                const unsigned* p = h1u + ((size_t)(t - 1) * DIM + tid) * 4;
                uint4v u;
                do { u = poll_load16(p); }
                while (u.x == SENT || u.y == SENT || u.z == SENT || u.w == SENT);
                hA[tid] = __builtin_bit_cast(f4v, u);
            } else {
                hA[tid] = f4v{0.f, 0.f, 0.f, 0.f};
            }
            __syncthreads();

            float a0 = 0.f, a1 = 0.f, a2 = 0.f, a3 = 0.f;
            const f4v* hp = &hA[s * 32];
            #pragma unroll
            for (int r = 0; r < 32; ++r) {
                const f4v v = hp[r];
                a0 += v.x * wr[r]; a1 += v.y * wr[r];
                a2 += v.z * wr[r]; a3 += v.w * wr[r];
            }
            part[s][0][j] = a0; part[s][1][j] = a1;
            part[s][2][j] = a2; part[s][3][j] = a3;
            __syncthreads();

            if (tid < 128) {
                float sum = xgv;
                #pragma unroll
                for (int s2 = 0; s2 < 16; ++s2) sum += part[s2][s][j];
                gate_lds[s][j] = sum;
            }
            __syncthreads();

            if (tid < 32) {
                const int ub = tid >> 3, ud = tid & 7;
                const float iv = gate_lds[ub][ 0 + ud];
                const float fv = gate_lds[ub][ 8 + ud];
                const float gv = gate_lds[ub][16 + ud];
                const float ov = gate_lds[ub][24 + ud];
                const float ig = fsig(iv);
                const float fg = fsig(fv);
                const float og = fsig(ov);
                c_reg = fg * c_reg + ig * ftanh_(gv);
                const float hval = og * ftanh_(c_reg);
                __hip_atomic_store(&h1c[((size_t)t * DIM + dbase + ud) * 4 + ub],
                                   hval, __ATOMIC_RELAXED, __HIP_MEMORY_SCOPE_AGENT);
            }
        }
    } else {
        for (int t = 0; t < TSEQ; ++t) {
            const unsigned* p1 = h1u + ((size_t)t * DIM + tid) * 4;
            uint4v u1;
            issue_load16(p1, &u1);        // fire h1[t]; completes under h2 poll/MAC1

            if (t > 0) {
                const unsigned* p = h2u + ((size_t)(t - 1) * DIM + tid) * 4;
                uint4v u;
                do { u = poll_load16(p); }
                while (u.x == SENT || u.y == SENT || u.z == SENT || u.w == SENT);
                hB[tid] = __builtin_bit_cast(f4v, u);
            } else {
                hB[tid] = f4v{0.f, 0.f, 0.f, 0.f};
            }
            __syncthreads();

            float a0 = 0.f, a1 = 0.f, a2 = 0.f, a3 = 0.f;
            {
                const f4v* hp = &hB[s * 32];
                #pragma unroll
                for (int r = 0; r < 32; ++r) {
                    const f4v v = hp[r];
                    a0 += v.x * wr[r]; a1 += v.y * wr[r];
                    a2 += v.z * wr[r]; a3 += v.w * wr[r];
                }
            }

            // complete the early h1[t] load; fallback poll only if cold
            wait_load16(&u1);
            if (u1.x == SENT || u1.y == SENT || u1.z == SENT || u1.w == SENT) {
                do { u1 = poll_load16(p1); }
                while (u1.x == SENT || u1.y == SENT || u1.z == SENT || u1.w == SENT);
            }
            hA[tid] = __builtin_bit_cast(f4v, u1);
            __syncthreads();
            {
                const f4v* hp = &hA[s * 32];
                #pragma unroll
                for (int r = 0; r < 32; ++r) {
                    const f4v v = hp[r];
                    a0 += v.x * wx[r]; a1 += v.y * wx[r];
                    a2 += v.z * wx[r]; a3 += v.w * wx[r];
                }
            }
            part[s][0][j] = a0; part[s][1][j] = a1;
            part[s][2][j] = a2; part[s][3][j] = a3;
            __syncthreads();

            if (tid < 128) {
                float sum = bias2;
                #pragma unroll
                for (int s2 = 0; s2 < 16; ++s2) sum += part[s2][s][j];
                gate_lds[s][j] = sum;
            }
            __syncthreads();

            if (tid < 32) {
                const int ub = tid >> 3, ud = tid & 7;
                const float iv = gate_lds[ub][ 0 + ud];
                const float fv = gate_lds[ub][ 8 + ud];
                const float gv = gate_lds[ub][16 + ud];
                const float ov = gate_lds[ub][24 + ud];
                const float ig = fsig(iv);
                const float fg = fsig(fv);
                const float og = fsig(ov);
                c_reg = fg * c_reg + ig * ftanh_(gv);
                const float hval = og * ftanh_(c_reg);
                __hip_atomic_store(&h2c[((size_t)t * DIM + dbase + ud) * 4 + ub],
                                   hval, __ATOMIC_RELAXED, __HIP_MEMORY_SCOPE_AGENT);
                hs2[((size_t)ub * TSEQ + t) * DIM + dbase + ud] = hval;
            }
        }
    }
}

// ---------------------------------------------------------------------------
// W[512][32000] f32 -> W'[32000][1024] bf16 pairs (wh, wl)   [R5, verified]
// ---------------------------------------------------------------------------
__global__ __launch_bounds__(256) void transpose_W(const float* __restrict__ W,
                                                   unsigned short* __restrict__ Wt)
{
    __shared__ float tile[32][256];
    const int tid = threadIdx.x;
    const int n0 = blockIdx.x * 256;
    const int k0 = blockIdx.y * 32;

    #pragma unroll 8
    for (int r = 0; r < 32; ++r)
        tile[r][tid] = W[(size_t)(k0 + r) * VOC + n0 + tid];
    __syncthreads();

    unsigned short pr[64];
    #pragma unroll
    for (int kk = 0; kk < 32; ++kk) {
        const float w = tile[kk][tid];
        const unsigned short h = f2bf(w);
        const unsigned short l = f2bf(w - bf2f(h));
        pr[2 * kk + 0] = h;
        pr[2 * kk + 1] = l;
    }
    unsigned short* dst = Wt + (size_t)(n0 + tid) * 1024 + 2 * k0;
    #pragma unroll
    for (int i = 0; i < 8; ++i)
        *(short8*)(dst + 8 * i) = *(short8*)&pr[8 * i];
}

// ---------------------------------------------------------------------------
// hs2[4096][512] f32 -> A'[4096][1024] bf16 pairs (ah, ah)   [R5, verified]
// ---------------------------------------------------------------------------
__global__ __launch_bounds__(64) void convert_A(const float* __restrict__ A,
                                                unsigned short* __restrict__ At)
{
    const int row = blockIdx.x;
    const int tid = threadIdx.x;
    const float4 v0 = *(const float4*)&A[(size_t)row * DIM + tid * 8];
    const float4 v1 = *(const float4*)&A[(size_t)row * DIM + tid * 8 + 4];
    float vals[8] = {v0.x, v0.y, v0.z, v0.w, v1.x, v1.y, v1.z, v1.w};
    unsigned short pr[16];
    #pragma unroll
    for (int i = 0; i < 8; ++i) {
        const unsigned short h = f2bf(vals[i]);
        pr[2 * i + 0] = h;
        pr[2 * i + 1] = h;
    }
    unsigned short* dst = At + (size_t)row * 1024 + tid * 16;
    #pragma unroll
    for (int i = 0; i < 2; ++i)
        *(short8*)(dst + 8 * i) = *(short8*)&pr[8 * i];
}

// ---------------------------------------------------------------------------
// Split-bf16 MFMA logits GEMM: C[4096][32000] = A'[4096][1024]·W'^T + bias
// [R5, verified: tail 0.58ms, absmax unchanged]
// ---------------------------------------------------------------------------
__global__ __launch_bounds__(256) void mfma_logits(
    const unsigned short* __restrict__ Ab, const unsigned short* __restrict__ Wb,
    const float* __restrict__ bias, float* __restrict__ C)
{
    constexpr int KP = 1024, BK = 64, NKT = KP / BK;
    __shared__ unsigned short As[128 * 64];
    __shared__ unsigned short Bs[128 * 64];

    const int tid  = threadIdx.x;
    const int lane = tid & 63;
    const int w    = tid >> 6;
    const int wm   = w >> 1, wn = w & 1;
    const int m0 = blockIdx.y * 128;
    const int n0 = blockIdx.x * 128;

    const int srow = tid >> 1;
    const int s0   = (tid & 1) * 4;
    const unsigned short* gA = Ab + (size_t)(m0 + srow) * KP + s0 * 8;
    const unsigned short* gB = Wb + (size_t)(n0 + srow) * KP + s0 * 8;
    const int swz = srow & 7;

    f32x4 acc[4][4] = {};
    short8 ra[4], rb[4];

    #pragma unroll
    for (int c = 0; c < 4; ++c) {
        ra[c] = *(const short8*)(gA + c * 8);
        rb[c] = *(const short8*)(gB + c * 8);
    }

    #pragma unroll 1
    for (int kt = 0; kt < NKT; ++kt) {
        __syncthreads();
        #pragma unroll
        for (int c = 0; c < 4; ++c) {
            *(short8*)&As[srow * 64 + ((s0 + c) ^ swz) * 8] = ra[c];
            *(short8*)&Bs[srow * 64 + ((s0 + c) ^ swz) * 8] = rb[c];
        }
        __syncthreads();

        if (kt + 1 < NKT) {
            const int ko = (kt + 1) * BK;
            #pragma unroll
            for (int c = 0; c < 4; ++c) {
                ra[c] = *(const short8*)(gA + ko + c * 8);
                rb[c] = *(const short8*)(gB + ko + c * 8);
            }
        }

        #pragma unroll
        for (int kk = 0; kk < 2; ++kk) {
            const int q = kk * 4 + (lane >> 4);
            short8 a[4], b[4];
            #pragma unroll
            for (int i = 0; i < 4; ++i) {
                const int Ra = wm * 64 + i * 16 + (lane & 15);
                a[i] = *(const short8*)&As[Ra * 64 + (q ^ (Ra & 7)) * 8];
                const int Rb = wn * 64 + i * 16 + (lane & 15);
                b[i] = *(const short8*)&Bs[Rb * 64 + (q ^ (Rb & 7)) * 8];
            }
            #pragma unroll
            for (int i = 0; i < 4; ++i)
                #pragma unroll
                for (int jx = 0; jx < 4; ++jx)
                    acc[i][jx] = __builtin_amdgcn_mfma_f32_16x16x32_bf16(
                        a[i], b[jx], acc[i][jx], 0, 0, 0);
        }
    }

    float bv[4];
    #pragma unroll
    for (int jx = 0; jx < 4; ++jx)
        bv[jx] = bias[n0 + wn * 64 + jx * 16 + (lane & 15)];

    #pragma unroll
    for (int i = 0; i < 4; ++i) {
        #pragma unroll
        for (int jx = 0; jx < 4; ++jx) {
            const int col = n0 + wn * 64 + jx * 16 + (lane & 15);
            #pragma unroll
            for (int r = 0; r < 4; ++r) {
                const int row = m0 + wm * 64 + i * 16 + (lane >> 4) * 4 + r;
                C[(size_t)row * VOC + col] = acc[i][jx][r] + bv[jx];
            }
        }
    }
}

// ---------------------------------------------------------------------------
extern "C" void kernel_launch(void* const* d_in, const int* in_sizes, int n_in,
                              void* d_out, int out_size, void* d_ws, size_t ws_size,
                              hipStream_t stream)
{
    const int*   tokens = (const int*)d_in[0];
    const float* embed  = (const float*)d_in[1];
    const float* Wx0    = (const float*)d_in[2];
    const float* Wh0    = (const float*)d_in[3];
    const float* b0     = (const float*)d_in[4];
    const float* Wx1    = (const float*)d_in[5];
    const float* Wh1    = (const float*)d_in[6];
    const float* b1     = (const float*)d_in[7];
    const float* Wout   = (const float*)d_in[8];
    const float* bout   = (const float*)d_in[9];
    float* out = (float*)d_out;

    char* ws = (char*)d_ws;
    float* x   = (float*)(ws);
    float* xg1 = (float*)(ws + ((size_t)8u << 20));
    float* h1c = (float*)(ws + ((size_t)40u << 20));
    float* h2c = (float*)(ws + ((size_t)48u << 20));
    float* hs2 = x;
    unsigned short* At = (unsigned short*)(ws + ((size_t)56u << 20));
    unsigned short* Wt = (unsigned short*)(ws + ((size_t)64u << 20));

    const bool use_mfma = ws_size >= ((size_t)132u << 20);

    hipMemsetAsync(ws + ((size_t)40u << 20), 0x7F, (size_t)16u << 20, stream);

    embed_kernel<<<dim3(4096), dim3(128), 0, stream>>>(tokens, embed, x);
    gemm_bias_f32<<<dim3(16, 32), dim3(256), 0, stream>>>(x, Wx0, b0, xg1, 4096, 2048, 512);

    if (use_mfma)
        transpose_W<<<dim3(125, 16), dim3(256), 0, stream>>>(Wout, Wt);

    lstm2_kernel<<<dim3(128), dim3(512), 0, stream>>>(xg1, Wh0, Wx1, Wh1, b1, h1c, h2c, hs2);

    if (use_mfma) {
        convert_A<<<dim3(4096), dim3(64), 0, stream>>>(hs2, At);
        mfma_logits<<<dim3(250, 32), dim3(256), 0, stream>>>(At, Wt, bout, out);
    } else {
        gemm_bias_f32<<<dim3(250, 32), dim3(256), 0, stream>>>(hs2, Wout, bout, out, 4096, VOC, 512);
    }
}